// Round 10
// baseline (294.744 us; speedup 1.0000x reference)
//
#include <hip/hip_runtime.h>
#include <hip/hip_cooperative_groups.h>

namespace cg = cooperative_groups;

#define GAMMA 0.1f
#define EPS_F 1e-12f

#define S_NODES 20000
#define SCAN_THREADS 1024
#define B_TARGET 51   // chunks per partition; P=5 -> grid 255 (1 block/CU, all-resident)

// ---- fused (cooperative) edge phase: SoA accumulators + rsq math ----
// SoA: accx/accy spread LDS atomics over all 32 banks (AoS float2 used 16).
// rsq: m = -2(r-1)/r * dr = (2/r - 2)*dr ; 1/r = rsq(d2); d2==0 -> 0 (matches
// F.normalize eps semantics within tolerance; absmax 4-8 passing since R2).
#define EDGE_S(dd, ss) do {                                      \
    int d_ = (dd);                                               \
    if (d_ >= lo && d_ < hi) {                                   \
        float2 xs = x[(ss)];                                     \
        float2 xd = x[d_];                                       \
        float dx = xd.x - xs.x;                                  \
        float dy = xd.y - xs.y;                                  \
        float d2 = dx * dx + dy * dy;                            \
        float ir = d2 > 0.f ? __builtin_amdgcn_rsqf(d2) : 0.f;   \
        float sc = 2.f * ir - 2.f;                               \
        atomicAdd(&accx[d_ - lo], sc * dx);                      \
        atomicAdd(&accy[d_ - lo], sc * dy);                      \
    }                                                            \
} while (0)

// One dispatch: scan phase (R0-proven structure) + grid.sync + reduce phase.
// Removes two launch boundaries (~7-10us each) vs the 2-kernel pipeline.
__global__ __launch_bounds__(SCAN_THREADS, 1)
void fused_kernel(const float2* __restrict__ x,
                  const int4* __restrict__ src4,
                  const int4* __restrict__ dst4,
                  const int* __restrict__ src,
                  const int* __restrict__ dst,
                  const float2* __restrict__ v,
                  float2* __restrict__ ws,
                  float2* __restrict__ out,
                  int e, int n, int B, int chunk) {
    __shared__ float accx[S_NODES];
    __shared__ float accy[S_NODES];
    int p = blockIdx.x / B;
    int b = blockIdx.x - p * B;
    int lo = p * S_NODES;
    int hi = min(lo + S_NODES, n);
    int tid = threadIdx.x;

    for (int i = tid; i < S_NODES; i += SCAN_THREADS) {
        accx[i] = 0.f;
        accy[i] = 0.f;
    }
    __syncthreads();

    int estart = b * chunk;
    int eend = min(estart + chunk, e);
    if (estart < eend) {
        int nvec = (eend - estart) >> 2;           // estart is 4-aligned
        const int4* d4p = dst4 + (estart >> 2);
        const int4* s4p = src4 + (estart >> 2);
        // two contiguous half-streams: 2 independent int4-pair loads in flight
        int nvec2 = nvec >> 1;
        for (int i = tid; i < nvec2; i += SCAN_THREADS) {
            int4 da = d4p[i];
            int4 sa = s4p[i];
            int4 db = d4p[i + nvec2];
            int4 sb = s4p[i + nvec2];
            EDGE_S(da.x, sa.x);
            EDGE_S(da.y, sa.y);
            EDGE_S(da.z, sa.z);
            EDGE_S(da.w, sa.w);
            EDGE_S(db.x, sb.x);
            EDGE_S(db.y, sb.y);
            EDGE_S(db.z, sb.z);
            EDGE_S(db.w, sb.w);
        }
        for (int i = (nvec2 << 1) + tid; i < nvec; i += SCAN_THREADS) {
            int4 d4 = d4p[i];
            int4 s4 = s4p[i];
            EDGE_S(d4.x, s4.x);
            EDGE_S(d4.y, s4.y);
            EDGE_S(d4.z, s4.z);
            EDGE_S(d4.w, s4.w);
        }
        for (int i = estart + (nvec << 2) + tid; i < eend; i += SCAN_THREADS)
            EDGE_S(dst[i], src[i]);
    }
    __syncthreads();

    // flush partials (coalesced float2 stores, same layout as legacy)
    float2* wsb = ws + (size_t)blockIdx.x * S_NODES;
    for (int i = tid; i < S_NODES; i += SCAN_THREADS)
        wsb[i] = make_float2(accx[i], accy[i]);

    __threadfence();              // device-scope release (cross-XCD visibility)
    cg::this_grid().sync();       // all partials visible to all blocks

    // ---- reduce phase (grid-stride; 255*1024 threads cover n=100K) ----
    int gsz = (int)(gridDim.x * SCAN_THREADS);
    for (int i = (int)blockIdx.x * SCAN_THREADS + tid; i < n; i += gsz) {
        int pp = i / S_NODES;
        int loc = i - pp * S_NODES;
        const float2* base = ws + ((size_t)(pp * B) * S_NODES + loc);
        float sx0 = 0.f, sy0 = 0.f, sx1 = 0.f, sy1 = 0.f;
        float sx2 = 0.f, sy2 = 0.f, sx3 = 0.f, sy3 = 0.f;
        int bb = 0;
        for (; bb + 8 <= B; bb += 8) {
            float2 t0 = base[(size_t)(bb + 0) * S_NODES];
            float2 t1 = base[(size_t)(bb + 1) * S_NODES];
            float2 t2 = base[(size_t)(bb + 2) * S_NODES];
            float2 t3 = base[(size_t)(bb + 3) * S_NODES];
            float2 t4 = base[(size_t)(bb + 4) * S_NODES];
            float2 t5 = base[(size_t)(bb + 5) * S_NODES];
            float2 t6 = base[(size_t)(bb + 6) * S_NODES];
            float2 t7 = base[(size_t)(bb + 7) * S_NODES];
            sx0 += t0.x; sy0 += t0.y; sx1 += t1.x; sy1 += t1.y;
            sx2 += t2.x; sy2 += t2.y; sx3 += t3.x; sy3 += t3.y;
            sx0 += t4.x; sy0 += t4.y; sx1 += t5.x; sy1 += t5.y;
            sx2 += t6.x; sy2 += t6.y; sx3 += t7.x; sy3 += t7.y;
        }
        for (; bb < B; ++bb) {
            float2 t = base[(size_t)bb * S_NODES];
            sx0 += t.x; sy0 += t.y;
        }
        float sx = (sx0 + sx1) + (sx2 + sx3);
        float sy = (sy0 + sy1) + (sy2 + sy3);
        float2 vi = v[i];
        out[i] = make_float2(sx - GAMMA * vi.x, sy - GAMMA * vi.y);
    }
}

// ================= legacy 2-kernel path (proven 127.7us; fallback) =================

#define EDGE(dd, ss) do {                                        \
    int d_ = (dd);                                               \
    if (d_ >= lo && d_ < hi) {                                   \
        float2 xs = x[(ss)];                                     \
        float2 xd = x[d_];                                       \
        float dx = xd.x - xs.x;                                  \
        float dy = xd.y - xs.y;                                  \
        float d2 = dx * dx + dy * dy;                            \
        float ir = d2 > 0.f ? __builtin_amdgcn_rsqf(d2) : 0.f;   \
        float sc = 2.f * ir - 2.f;                               \
        atomicAdd(&accx[d_ - lo], sc * dx);                      \
        atomicAdd(&accy[d_ - lo], sc * dy);                      \
    }                                                            \
} while (0)

__global__ __launch_bounds__(SCAN_THREADS, 1)
void scan_kernel(const float2* __restrict__ x,
                 const int4* __restrict__ src4,
                 const int4* __restrict__ dst4,
                 const int* __restrict__ src,
                 const int* __restrict__ dst,
                 float2* __restrict__ ws,
                 int e, int n, int B, int chunk) {
    __shared__ float accx[S_NODES];
    __shared__ float accy[S_NODES];
    int p = blockIdx.x / B;
    int b = blockIdx.x - p * B;
    int lo = p * S_NODES;
    int hi = min(lo + S_NODES, n);
    int tid = threadIdx.x;

    for (int i = tid; i < S_NODES; i += SCAN_THREADS) {
        accx[i] = 0.f;
        accy[i] = 0.f;
    }
    __syncthreads();

    int estart = b * chunk;
    int eend = min(estart + chunk, e);
    if (estart < eend) {
        int nvec = (eend - estart) >> 2;
        const int4* d4p = dst4 + (estart >> 2);
        const int4* s4p = src4 + (estart >> 2);
        int nvec2 = nvec >> 1;
        for (int i = tid; i < nvec2; i += SCAN_THREADS) {
            int4 da = d4p[i];
            int4 sa = s4p[i];
            int4 db = d4p[i + nvec2];
            int4 sb = s4p[i + nvec2];
            EDGE(da.x, sa.x);
            EDGE(da.y, sa.y);
            EDGE(da.z, sa.z);
            EDGE(da.w, sa.w);
            EDGE(db.x, sb.x);
            EDGE(db.y, sb.y);
            EDGE(db.z, sb.z);
            EDGE(db.w, sb.w);
        }
        for (int i = (nvec2 << 1) + tid; i < nvec; i += SCAN_THREADS) {
            int4 d4 = d4p[i];
            int4 s4 = s4p[i];
            EDGE(d4.x, s4.x);
            EDGE(d4.y, s4.y);
            EDGE(d4.z, s4.z);
            EDGE(d4.w, s4.w);
        }
        for (int i = estart + (nvec << 2) + tid; i < eend; i += SCAN_THREADS)
            EDGE(dst[i], src[i]);
    }
    __syncthreads();

    float2* wsb = ws + (size_t)blockIdx.x * S_NODES;
    for (int i = tid; i < S_NODES; i += SCAN_THREADS)
        wsb[i] = make_float2(accx[i], accy[i]);
}

__global__ __launch_bounds__(256)
void reduce_kernel(const float2* __restrict__ ws,
                   const float2* __restrict__ v,
                   float2* __restrict__ out,
                   int n, int B) {
    int i = blockIdx.x * blockDim.x + threadIdx.x;
    if (i >= n) return;
    int p = i / S_NODES;
    int loc = i - p * S_NODES;
    const float2* base = ws + ((size_t)(p * B) * S_NODES + loc);
    float sx0 = 0.f, sy0 = 0.f, sx1 = 0.f, sy1 = 0.f;
    float sx2 = 0.f, sy2 = 0.f, sx3 = 0.f, sy3 = 0.f;
    int b = 0;
    for (; b + 8 <= B; b += 8) {
        float2 t0 = base[(size_t)(b + 0) * S_NODES];
        float2 t1 = base[(size_t)(b + 1) * S_NODES];
        float2 t2 = base[(size_t)(b + 2) * S_NODES];
        float2 t3 = base[(size_t)(b + 3) * S_NODES];
        float2 t4 = base[(size_t)(b + 4) * S_NODES];
        float2 t5 = base[(size_t)(b + 5) * S_NODES];
        float2 t6 = base[(size_t)(b + 6) * S_NODES];
        float2 t7 = base[(size_t)(b + 7) * S_NODES];
        sx0 += t0.x; sy0 += t0.y; sx1 += t1.x; sy1 += t1.y;
        sx2 += t2.x; sy2 += t2.y; sx3 += t3.x; sy3 += t3.y;
        sx0 += t4.x; sy0 += t4.y; sx1 += t5.x; sy1 += t5.y;
        sx2 += t6.x; sy2 += t6.y; sx3 += t7.x; sy3 += t7.y;
    }
    for (; b < B; ++b) {
        float2 t = base[(size_t)b * S_NODES];
        sx0 += t.x; sy0 += t.y;
    }
    float sx = (sx0 + sx1) + (sx2 + sx3);
    float sy = (sy0 + sy1) + (sy2 + sy3);
    float2 vi = v[i];
    out[i] = make_float2(sx - GAMMA * vi.x, sy - GAMMA * vi.y);
}

// ---------- tiny-workspace fallback (global atomics) ----------
__global__ void init_out_kernel(const float2* __restrict__ v,
                                float2* __restrict__ out, int n) {
    int i = blockIdx.x * blockDim.x + threadIdx.x;
    if (i < n) {
        float2 vi = v[i];
        out[i] = make_float2(-GAMMA * vi.x, -GAMMA * vi.y);
    }
}

__device__ __forceinline__ void do_edge_atomic(const float2* __restrict__ x,
                                               int s, int d,
                                               float* __restrict__ out) {
    float2 xs = x[s];
    float2 xd = x[d];
    float dx = xd.x - xs.x;
    float dy = xd.y - xs.y;
    float r = sqrtf(dx * dx + dy * dy);
    float sc = -2.0f * (r - 1.0f) / fmaxf(r, EPS_F);
    atomicAdd(&out[2 * d], sc * dx);
    atomicAdd(&out[2 * d + 1], sc * dy);
}

__global__ void edge_kernel_atomic(const float2* __restrict__ x,
                                   const int4* __restrict__ src4,
                                   const int4* __restrict__ dst4,
                                   const int* __restrict__ src,
                                   const int* __restrict__ dst,
                                   float* __restrict__ out,
                                   int e4, int e_total) {
    int i = blockIdx.x * blockDim.x + threadIdx.x;
    if (i < e4) {
        int4 s = src4[i];
        int4 d = dst4[i];
        do_edge_atomic(x, s.x, d.x, out);
        do_edge_atomic(x, s.y, d.y, out);
        do_edge_atomic(x, s.z, d.z, out);
        do_edge_atomic(x, s.w, d.w, out);
    }
    if (i == 0) {
        for (int e = e4 * 4; e < e_total; ++e)
            do_edge_atomic(x, src[e], dst[e], out);
    }
}

extern "C" void kernel_launch(void* const* d_in, const int* in_sizes, int n_in,
                              void* d_out, int out_size, void* d_ws, size_t ws_size,
                              hipStream_t stream) {
    const float2* x = (const float2*)d_in[0];   // [N,2] fp32
    const float2* v = (const float2*)d_in[1];   // [N,2] fp32
    const int* src  = (const int*)d_in[2];      // [E] int32
    const int* dst  = (const int*)d_in[3];      // [E] int32

    int n = in_sizes[0] / 2;   // N nodes
    int e = in_sizes[2];       // E edges

    float2* out = (float2*)d_out;
    float2* ws  = (float2*)d_ws;

    int P = (n + S_NODES - 1) / S_NODES;
    size_t per_b = (size_t)P * S_NODES * sizeof(float2);
    int Bmax = (per_b > 0) ? (int)(ws_size / per_b) : 0;
    int B = B_TARGET < Bmax ? B_TARGET : Bmax;
    if (P >= 1 && B > 256 / P) B = 256 / P;      // cooperative residency cap

    if (B >= 1) {
        int chunk = (((e + B - 1) / B) + 3) & ~3;   // 4-aligned chunk per block
        int grid = P * B;                            // <=256: 1 block/CU resident

        // ---- single cooperative dispatch: scan + grid.sync + reduce ----
        const int4* src4 = (const int4*)src;
        const int4* dst4 = (const int4*)dst;
        void* args[] = { (void*)&x, (void*)&src4, (void*)&dst4,
                         (void*)&src, (void*)&dst, (void*)&v,
                         (void*)&ws, (void*)&out,
                         (void*)&e, (void*)&n, (void*)&B, (void*)&chunk };
        hipError_t err = hipLaunchCooperativeKernel(
            (const void*)fused_kernel, dim3(grid), dim3(SCAN_THREADS),
            args, 0, stream);
        if (err == hipSuccess) return;

        // cooperative unavailable -> proven 2-kernel pipeline
        scan_kernel<<<grid, SCAN_THREADS, 0, stream>>>(
            x, src4, dst4, src, dst, ws, e, n, B, chunk);
        int threads = 256;
        reduce_kernel<<<(n + threads - 1) / threads, threads, 0, stream>>>(
            ws, v, out, n, B);
    } else {
        // workspace too small: direct-atomic path
        int threads = 256;
        init_out_kernel<<<(n + threads - 1) / threads, threads, 0, stream>>>(
            v, out, n);
        int e4 = e / 4;
        int blocks = (e4 + threads - 1) / threads;
        if (blocks < 1) blocks = 1;
        edge_kernel_atomic<<<blocks, threads, 0, stream>>>(
            x, (const int4*)src, (const int4*)dst, src, dst,
            (float*)d_out, e4, e);
    }
}